// Round 15
// baseline (99.941 us; speedup 1.0000x reference)
//
#include <hip/hip_runtime.h>

typedef __bf16 bf16;
typedef __attribute__((ext_vector_type(8))) short short8;
typedef __attribute__((ext_vector_type(4))) short short4v;
typedef __attribute__((ext_vector_type(4))) float floatx4;

#define DEVINL __device__ __forceinline__

// async global->LDS, 16B per lane. LDS dest = wave-uniform base + lane*16.
DEVINL void gll16(const void* g, void* l) {
  __builtin_amdgcn_global_load_lds((const __attribute__((address_space(1))) void*)g,
                                   (__attribute__((address_space(3))) void*)l, 16, 0, 0);
}

DEVINL float fast_exp2(float x) { return __builtin_amdgcn_exp2f(x); }

// scale * log2(e), folded into Q at projection time
#define QSCALE 0.18033688011112042f

// ---------------- fused prep: x->bf16 (blocks 0..2047) + weight transposes (2048..3071) ----
__global__ __launch_bounds__(256) void prep_all(const float* __restrict__ x,
                                                const float* __restrict__ Wq,
                                                const float* __restrict__ Wk,
                                                const float* __restrict__ Wv,
                                                const float* __restrict__ Wo,
                                                bf16* __restrict__ x_bf,
                                                bf16* __restrict__ WbigT,
                                                bf16* __restrict__ WoT) {
  __shared__ float tile[64][65];
  int bid = blockIdx.x;
  if (bid < 2048) {
    int i = (bid * 256 + threadIdx.x) * 8;
    float4 a = *(const float4*)(x + i);
    float4 b = *(const float4*)(x + i + 4);
    union { bf16 h[8]; short8 s; } u;
    u.h[0] = (bf16)a.x; u.h[1] = (bf16)a.y; u.h[2] = (bf16)a.z; u.h[3] = (bf16)a.w;
    u.h[4] = (bf16)b.x; u.h[5] = (bf16)b.y; u.h[6] = (bf16)b.z; u.h[7] = (bf16)b.w;
    *(short8*)(x_bf + i) = u.s;
    return;
  }
  int t = bid - 2048;
  int which = t >> 8;         // 0..3
  t &= 255;
  const float* in;
  bf16* out;
  int C, tilesC, tilesPerBatch;
  long inStride;
  if (which < 3) {
    in = which == 0 ? Wq : (which == 1 ? Wk : Wv);
    out = WbigT + (long)which * 1024 * 1024;
    C = 64; tilesC = 1; tilesPerBatch = 16; inStride = 65536;
  } else {
    in = Wo; out = WoT;
    C = 1024; tilesC = 16; tilesPerBatch = 256; inStride = 0;
  }
  int batch = t / tilesPerBatch;
  int tt = t % tilesPerBatch;
  int ri = tt / tilesC, ci = tt % tilesC;
  const float* src = in + batch * inStride;
  bf16* dst = out + batch * (long)65536 * (which < 3 ? 1 : 0);
  int tx = threadIdx.x & 63, ty = threadIdx.x >> 6;
#pragma unroll
  for (int i = 0; i < 16; i++) {
    int r = ty + i * 4;
    tile[r][tx] = src[(long)(ri * 64 + r) * C + ci * 64 + tx];
  }
  __syncthreads();
#pragma unroll
  for (int i = 0; i < 16; i++) {
    int c = ty + i * 4;
    dst[(long)(ci * 64 + c) * 1024 + ri * 64 + tx] = (bf16)tile[tx][c];
  }
}

// ---------------- QKV GEMM: 256x192 tile, BK=64, 8-phase counted-vmcnt schedule --------
// (R14-verified race-free schedule; see comments there.)
__global__ __launch_bounds__(512, 2) void gemm256_qkv(const bf16* __restrict__ A,
                                                      const bf16* __restrict__ BT,
                                                      bf16* __restrict__ q_ws,
                                                      bf16* __restrict__ k_ws,
                                                      bf16* __restrict__ v_ws) {
  extern __shared__ char lds[];
  int swz = (blockIdx.x & 7) * 32 + (blockIdx.x >> 3);  // grid 256, XCD swizzle
  int bm = swz >> 4, bn = swz & 15;
  int tid = threadIdx.x, lane = tid & 63, wid = tid >> 6;
  int wm = wid >> 2, wn = wid & 3;
  int ql = lane & 15, g = lane >> 4;
  int sw = (ql & 7) << 4;
  char* ldsA = lds;            // [slot][half] 2*2*16KB = 64KB
  char* ldsB = lds + 65536;    // [slot] 2*24KB = 48KB

  const char* Abase = (const char*)A + (long)bm * 256 * 2048;
  const char* Bbase = (const char*)BT + (long)bn * 192 * 2048;
  int scb = ((tid & 7) * 16) ^ (((tid >> 3) & 7) << 4);  // pre-swizzled source col

  floatx4 acc[8][3] = {};
  short8 aF[4], bF[3];

#define STGA(kt_, h_) do {                                                         \
    _Pragma("unroll") for (int j_ = 0; j_ < 2; j_++)                               \
      gll16(Abase + (long)((h_) * 128 + j_ * 64 + (tid >> 3)) * 2048               \
                   + (kt_) * 128 + scb,                                            \
            ldsA + ((kt_) & 1) * 32768 + (h_) * 16384 + j_ * 8192 + wid * 1024);   \
  } while (0)
#define STGB(kt_, c_)                                                              \
    gll16(Bbase + (long)((c_) * 64 + (tid >> 3)) * 2048 + (kt_) * 128 + scb,       \
          ldsB + ((kt_) & 1) * 24576 + (c_) * 8192 + wid * 1024)
#define LDA(slot_, frh_, kk_) do {                                                 \
    _Pragma("unroll") for (int j_ = 0; j_ < 4; j_++)                               \
      aF[j_] = *(const short8*)(ldsA + (slot_) * 32768 + wm * 16384 +              \
               (((frh_) * 4 + j_) * 16 + ql) * 128 + (((kk_) * 64 + g * 16) ^ sw));\
  } while (0)
#define LDB(slot_, kk_) do {                                                       \
    _Pragma("unroll") for (int f_ = 0; f_ < 3; f_++)                               \
      bF[f_] = *(const short8*)(ldsB + (slot_) * 24576 +                           \
               (wn * 48 + f_ * 16 + ql) * 128 + (((kk_) * 64 + g * 16) ^ sw));     \
  } while (0)
#define MFMA12(frh_) do {                                                          \
    __builtin_amdgcn_s_setprio(1);                                                 \
    _Pragma("unroll") for (int j_ = 0; j_ < 4; j_++)                               \
      _Pragma("unroll") for (int f_ = 0; f_ < 3; f_++)                             \
        acc[(frh_) * 4 + j_][f_] = __builtin_amdgcn_mfma_f32_16x16x32_bf16(        \
            aF[j_], bF[f_], acc[(frh_) * 4 + j_][f_], 0, 0, 0);                    \
    __builtin_amdgcn_s_setprio(0);                                                 \
  } while (0)
#define BAR __builtin_amdgcn_s_barrier()
#define LG0 asm volatile("s_waitcnt lgkmcnt(0)" ::: "memory")

  // prologue: B(0):3, A(0):4, B(1):3 = 10 loads
  STGB(0, 0); STGB(0, 1); STGB(0, 2);
  STGA(0, 0); STGA(0, 1);
  STGB(1, 0); STGB(1, 1); STGB(1, 2);

  for (int it = 0; it < 8; it++) {
    int b1 = 2 * it + 1, a2 = 2 * it + 2, b2 = 2 * it + 3;
    bool more = it < 7;
    // P1
    asm volatile("s_waitcnt vmcnt(3)" ::: "memory");
    BAR;
    LDA(0, 0, 0); LDB(0, 0);
    STGA(b1, 0);
    BAR; LG0; MFMA12(0); BAR;
    // P2
    LDA(0, 1, 0);
    STGA(b1, 1);
    BAR; LG0; MFMA12(1); BAR;
    // P3 — no stage
    LDA(0, 0, 1); LDB(0, 1);
    BAR; LG0; MFMA12(0); BAR;
    // P4
    LDA(0, 1, 1);
    if (more) { STGB(a2, 0); STGB(a2, 1); STGB(a2, 2); }
    BAR; LG0; MFMA12(1); BAR;
    // P5
    if (more) { asm volatile("s_waitcnt vmcnt(3)" ::: "memory"); }
    else      { asm volatile("s_waitcnt vmcnt(0)" ::: "memory"); }
    BAR;
    LDA(1, 0, 0); LDB(1, 0);
    if (more) STGA(a2, 0);
    BAR; LG0; MFMA12(0); BAR;
    // P6
    LDA(1, 1, 0);
    if (more) STGA(a2, 1);
    BAR; LG0; MFMA12(1); BAR;
    // P7 — no stage
    LDA(1, 0, 1); LDB(1, 1);
    BAR; LG0; MFMA12(0); BAR;
    // P8
    LDA(1, 1, 1);
    if (more) { STGB(b2, 0); STGB(b2, 1); STGB(b2, 2); }
    BAR; LG0; MFMA12(1); BAR;
  }
#undef STGA
#undef STGB
#undef LDA
#undef LDB
#undef MFMA12
#undef BAR
#undef LG0

  // ---- epilogue ----
#pragma unroll
  for (int fr = 0; fr < 8; fr++)
#pragma unroll
    for (int fc = 0; fc < 3; fc++) {
      int local_c = wn * 48 + fc * 16 + ql;
      int cg = bn * 192 + local_c;
      if (cg < 2048) {
        bf16* dst = (cg < 1024) ? q_ws : k_ws;
        float scale = (cg < 1024) ? QSCALE : 1.0f;
        int h = (cg >> 6) & 15, e = cg & 63;
#pragma unroll
        for (int i = 0; i < 4; i++) {
          int r = bm * 256 + wm * 128 + fr * 16 + g * 4 + i;
          int b = r >> 11, s = r & 2047;
          long bh = (long)b * 16 + h;
          dst[(bh * 2048 + s) * 64 + e] = (bf16)(acc[fr][fc][i] * scale);
        }
      }
    }

  if (bn >= 10) {
    __syncthreads();
#pragma unroll
    for (int fr = 0; fr < 8; fr++)
#pragma unroll
      for (int fc = 0; fc < 3; fc++) {
        int local_c = wn * 48 + fc * 16 + ql;
        int cg = bn * 192 + local_c;
        if (cg >= 2048) {
          int ls0 = wm * 128 + fr * 16 + g * 4;
          int s6 = ls0 & 63;
          // sigma16: key 32kk+16b'+4g+r' -> pos 32kk+8g+4b'+r'
          int sp = (ls0 & ~63) | (s6 & 35) | ((s6 & 12) << 1) | ((s6 & 16) >> 2);
          union { bf16 hh[4]; short4v s4; } u;
#pragma unroll
          for (int i = 0; i < 4; i++) u.hh[i] = (bf16)acc[fr][fc][i];
          *(short4v*)(lds + local_c * 512 + ((sp * 2) ^ ((local_c & 7) << 4))) = u.s4;
        }
      }
    __syncthreads();
    int b = bm >> 3;
    long sbase = (long)(bm & 7) * 256;
#pragma unroll
    for (int j = 0; j < 12; j++) {
      int local_c = wid * 24 + j * 2 + (lane >> 5);
      int cg = bn * 192 + local_c;
      if (cg >= 2048) {
        int chunk = lane & 31;
        int h = (cg >> 6) & 15, e = cg & 63;
        long bh = (long)b * 16 + h;
        char* dstp = (char*)v_ws + ((bh * 64 + e) * 2048 + sbase) * 2 + chunk * 16;
        *(short8*)dstp = *(const short8*)(lds + local_c * 512 + ((chunk * 16) ^ ((local_c & 7) << 4)));
      }
    }
  }
}

// ---------------- GEMM (output projection): 128x128 tile, 4 waves, 2-phase pipelined ----
__global__ __launch_bounds__(256) void gemm_out(const bf16* __restrict__ A,
                                                const bf16* __restrict__ BT,
                                                float* __restrict__ Cout,
                                                int N, int gridN) {
  int cpx = gridDim.x >> 3;
  int swz = (blockIdx.x & 7) * cpx + (blockIdx.x >> 3);
  int bm = swz / gridN, bn = swz % gridN;
  __shared__ char lds[65536];  // A slots @0,16K ; B slots @32K,48K
  int tid = threadIdx.x;
  int lane = tid & 63, wid = tid >> 6;
  int wr = wid >> 1, wc = wid & 1;
  floatx4 acc[4][4] = {};
  const char* Abase = (const char*)A + (long)bm * 128 * 2048;
  const char* Bbase = (const char*)BT + (long)bn * 128 * 2048;
  int scb = ((tid & 7) * 16) ^ (((tid >> 3) & 7) << 4);

#define OSTG(kt_) do {                                                             \
    char* la_ = lds + ((kt_) & 1) * 16384;                                         \
    char* lb_ = lds + 32768 + ((kt_) & 1) * 16384;                                 \
    _Pragma("unroll") for (int q_ = 0; q_ < 4; q_++) {                             \
      gll16(Abase + (long)(q_ * 32 + (tid >> 3)) * 2048 + (kt_) * 128 + scb,       \
            la_ + q_ * 4096 + wid * 1024);                                         \
      gll16(Bbase + (long)(q_ * 32 + (tid >> 3)) * 2048 + (kt_) * 128 + scb,       \
            lb_ + q_ * 4096 + wid * 1024);                                         \
    }                                                                              \
  } while (0)

  OSTG(0);
  for (int kt = 0; kt < 16; kt++) {
    if (kt < 15) {
      OSTG(kt + 1);
      asm volatile("s_waitcnt vmcnt(8)" ::: "memory");
    } else {
      asm volatile("s_waitcnt vmcnt(0)" ::: "memory");
    }
    __builtin_amdgcn_s_barrier();
    char* la = lds + (kt & 1) * 16384;
    char* lb = lds + 32768 + (kt & 1) * 16384;
#pragma unroll
    for (int kk = 0; kk < 2; kk++) {
      short8 a[4], b[4];
#pragma unroll
      for (int mi = 0; mi < 4; mi++) {
        int row = wr * 64 + mi * 16 + (lane & 15);
        int col = (kk * 64 + (lane >> 4) * 16) ^ ((row & 7) << 4);
        a[mi] = *(const short8*)(la + row * 128 + col);
      }
#pragma unroll
      for (int ni = 0; ni < 4; ni++) {
        int row = wc * 64 + ni * 16 + (lane & 15);
        int col = (kk * 64 + (lane >> 4) * 16) ^ ((row & 7) << 4);
        b[ni] = *(const short8*)(lb + row * 128 + col);
      }
#pragma unroll
      for (int mi = 0; mi < 4; mi++)
#pragma unroll
        for (int ni = 0; ni < 4; ni++)
          acc[mi][ni] = __builtin_amdgcn_mfma_f32_16x16x32_bf16(a[mi], b[ni], acc[mi][ni], 0, 0, 0);
    }
    __builtin_amdgcn_s_barrier();
  }
#undef OSTG

#pragma unroll
  for (int mi = 0; mi < 4; mi++)
#pragma unroll
    for (int ni = 0; ni < 4; ni++)
#pragma unroll
      for (int i = 0; i < 4; i++) {
        int r = bm * 128 + wr * 64 + mi * 16 + (lane >> 4) * 4 + i;
        int c = bn * 128 + wc * 64 + ni * 16 + (lane & 15);
        Cout[(long)r * N + c] = acc[mi][ni][i];
      }
}

// ---------------- flash attention: KV-split x2, 1024-thread block, VALU-l softmax ------
// R9/R12/R14-verified structure; change: l accumulated in VALU during SMSTEP (per-lane
// scalar over this lane's 16 keys/leg) instead of 4 mfma(ones,P) per leg (-11% MFMA,
// shorter PV fence). End: l = ls + shfl_xor(16) + shfl_xor(32) (R10/R11-verified pattern).
__global__ __launch_bounds__(1024, 4) void attn_kernel(const bf16* __restrict__ q_ws,
                                                       const bf16* __restrict__ k_ws,
                                                       const bf16* __restrict__ v_ws,
                                                       bf16* __restrict__ obuf) {
  extern __shared__ char lds[];  // [grp][ kbuf 4x8KB | vbuf 4x8KB ] = 2 x 64KB
  int wgid = ((blockIdx.x & 7) << 5) + (blockIdx.x >> 3);  // bijective, 256 = 8*32
  int qt = wgid & 7;
  int bh = wgid >> 3;
  int b = bh >> 4, h = bh & 15;
  int tid = threadIdx.x, lane = tid & 63, wid = tid >> 6;  // wid 0..15
  int grp = wid >> 3, w8 = wid & 7;
  int ql = lane & 15, g = lane >> 4;
  char* kbuf = lds + grp * 65536;
  char* vbuf = kbuf + 32768;

  const char* kbase = (const char*)k_ws + (long)bh * 2048 * 128 + (long)grp * 16 * 64 * 128;
  const char* vbase = (const char*)v_ws + (long)bh * 64 * 4096 + (long)grp * 16 * 128;

  int srow = w8 * 8 + (lane >> 3);
  int scb = ((lane & 7) * 16) ^ (((lane >> 3) & 7) << 4);

#define STAGE(t_) do {                                                              \
    gll16(kbase + ((long)(t_) * 64 + srow) * 128 + scb,                             \
          kbuf + ((t_) & 3) * 8192 + w8 * 1024);                                    \
    gll16(vbase + (long)srow * 4096 + (long)(t_) * 128 + scb,                       \
          vbuf + ((t_) & 3) * 8192 + w8 * 1024);                                    \
  } while (0)

#define WAIT2_BAR do {                                                              \
    asm volatile("s_waitcnt vmcnt(2)" ::: "memory");                                \
    __builtin_amdgcn_s_barrier();                                                   \
    asm volatile("" ::: "memory");                                                  \
  } while (0)

  int sw = (ql & 7) << 4;
  int fof0 = ql * 128 + ((g * 16) ^ sw);        // kk = 0
  int fof1 = ql * 128 + ((64 + g * 16) ^ sw);   // kk = 1

  const bf16* qrowL = q_ws + ((long)bh * 2048 + qt * 256 + w8 * 32 + ql) * 64 + 8 * g;
  short8 qL0 = *(const short8*)(qrowL);
  short8 qL1 = *(const short8*)(qrowL + 32);
  short8 qH0 = *(const short8*)(qrowL + 1024);       // +16 rows
  short8 qH1 = *(const short8*)(qrowL + 1024 + 32);

  float lLs = 0.f, lHs = 0.f;
  floatx4 oL[4] = {}, oH[4] = {};
  floatx4 saL[4], saH[4];
  short8 pbL[2], pbH[2];

#define QKSTEP(kc) do {                                                             \
    __builtin_amdgcn_s_setprio(1);                                                  \
    _Pragma("unroll") for (int t_ = 0; t_ < 4; t_++) {                              \
      short8 kf = *(const short8*)((kc) + fof0 + t_ * 2048);                        \
      saL[t_] = __builtin_amdgcn_mfma_f32_16x16x32_bf16(kf, qL0, (floatx4){}, 0, 0, 0); \
      saH[t_] = __builtin_amdgcn_mfma_f32_16x16x32_bf16(kf, qH0, (floatx4){}, 0, 0, 0); \
    }                                                                               \
    _Pragma("unroll") for (int t_ = 0; t_ < 4; t_++) {                              \
      short8 kf = *(const short8*)((kc) + fof1 + t_ * 2048);                        \
      saL[t_] = __builtin_amdgcn_mfma_f32_16x16x32_bf16(kf, qL1, saL[t_], 0, 0, 0); \
      saH[t_] = __builtin_amdgcn_mfma_f32_16x16x32_bf16(kf, qH1, saH[t_], 0, 0, 0); \
    }                                                                               \
    __builtin_amdgcn_s_setprio(0);                                                  \
  } while (0)

  // max-free softmax; l accumulated per-lane in VALU (guard: rescale never fires for
  // bounded scores; per-lane-partial check is conservative)
#define SM_HALF(sa, pb, l_s, o_acc) do {                                            \
    if (__builtin_expect(l_s > 1e30f, 0)) {                                         \
      const float c_ = 7.8886091e-31f; /* 2^-100 */                                 \
      _Pragma("unroll") for (int t_ = 0; t_ < 4; t_++)                              \
        _Pragma("unroll") for (int i_ = 0; i_ < 4; i_++) o_acc[t_][i_] *= c_;       \
      l_s *= c_;                                                                    \
    }                                                                               \
    _Pragma("unroll") for (int kk_ = 0; kk_ < 2; kk_++) {                           \
      union { bf16 hh[8]; short8 s; } up_;                                          \
      _Pragma("unroll") for (int r_ = 0; r_ < 4; r_++) {                            \
        float e_ = fast_exp2(sa[2 * kk_][r_]);                                      \
        l_s += e_; up_.hh[r_] = (bf16)e_;                                           \
      }                                                                             \
      _Pragma("unroll") for (int r_ = 0; r_ < 4; r_++) {                            \
        float e_ = fast_exp2(sa[2 * kk_ + 1][r_]);                                  \
        l_s += e_; up_.hh[4 + r_] = (bf16)e_;                                       \
      }                                                                             \
      pb[kk_] = up_.s;                                                              \
    }                                                                               \
  } while (0)

#define SMSTEP do { SM_HALF(saL, pbL, lLs, oL); SM_HALF(saH, pbH, lHs, oH); } while (0)

#define PVSTEP(vc) do {                                                             \
    __builtin_amdgcn_s_setprio(1);                                                  \
    _Pragma("unroll") for (int t_ = 0; t_ < 4; t_++) {                              \
      short8 vf = *(const short8*)((vc) + fof0 + t_ * 2048);                        \
      oL[t_] = __builtin_amdgcn_mfma_f32_16x16x32_bf16(vf, pbL[0], oL[t_], 0, 0, 0);\
      oH[t_] = __builtin_amdgcn_mfma_f32_16x16x32_bf16(vf, pbH[0], oH[t_], 0, 0, 0);\
    }                                                                               \
    _Pragma("unroll") for (int t_ = 0; t_ < 4; t_++) {                              \
      short8 vf = *(const short8*)((vc) + fof1 + t_ * 2048);                        \
      oL[t_] = __builtin_amdgcn_mfma_f32_16x16x32_bf16(vf, pbL[1], oL[t_], 0, 0, 0);\
      oH[t_] = __builtin_amdgcn_mfma_f32_16x16x32_bf16(vf, pbH[1], oH[t_], 0, 0, 0);\
    }                                                                               \
    __builtin_amdgcn_s_setprio(0);                                                  \
  } while (0)

  // ---- prologue ----
  STAGE(0); STAGE(1);
  WAIT2_BAR;
  QKSTEP(kbuf + 0 * 8192);
  STAGE(2);
  SMSTEP;
  WAIT2_BAR;
  STAGE(3);
  QKSTEP(kbuf + 1 * 8192);

  // ---- main loop: legs t = 1..13 ----
  for (int t = 1; t <= 13; t++) {
    PVSTEP(vbuf + ((t - 1) & 3) * 8192);
    SMSTEP;
    WAIT2_BAR;
    if (t <= 12) STAGE(t + 3);
    QKSTEP(kbuf + ((t + 1) & 3) * 8192);
  }

  // ---- leg 14 (drain to 0 for the last tile) ----
  PVSTEP(vbuf + (13 & 3) * 8192);
  SMSTEP;
  __syncthreads();               // vmcnt(0): tile 15 landed
  QKSTEP(kbuf + (15 & 3) * 8192);

  // ---- leg 15 ----
  PVSTEP(vbuf + (14 & 3) * 8192);
  SMSTEP;
  PVSTEP(vbuf + (15 & 3) * 8192);

#undef STAGE
#undef WAIT2_BAR
#undef QKSTEP
#undef SM_HALF
#undef SMSTEP
#undef PVSTEP

  // ---- reduce per-lane l partials across the 4 g-groups (same q=ql) ----
  float lL = lLs;
  lL += __shfl_xor(lL, 16);
  lL += __shfl_xor(lL, 32);
  float lH = lHs;
  lH += __shfl_xor(lH, 16);
  lH += __shfl_xor(lH, 32);

  // ---- combine: O = O0 + O1, l = l0 + l1 (all K/V buffers dead) ----
  __syncthreads();
  if (grp == 1) {
    char* pbase = lds + 65536 + w8 * 8192;  // group 1's own (dead) region
#pragma unroll
    for (int t = 0; t < 4; t++) {
      *(floatx4*)(pbase + (t * 2 + 0) * 1024 + lane * 16) = oL[t];
      *(floatx4*)(pbase + (t * 2 + 1) * 1024 + lane * 16) = oH[t];
    }
    *(float2*)(lds + w8 * 512 + lane * 8) = make_float2(lL, lH);
  }
  __syncthreads();
  if (grp == 0) {
    float2 lp = *(const float2*)(lds + w8 * 512 + lane * 8);
    const char* pbase = lds + 65536 + w8 * 8192;
    float invL = 1.f / (lL + lp.x);
    float invH = 1.f / (lH + lp.y);
    int s = qt * 256 + w8 * 32 + ql;
    bf16* orowL = obuf + ((long)b * 2048 + s) * 1024 + h * 64;
    bf16* orowH = orowL + 16 * 1024;
#pragma unroll
    for (int t = 0; t < 4; t++) {
      floatx4 aL = *(const floatx4*)(pbase + (t * 2 + 0) * 1024 + lane * 16);
      floatx4 aH = *(const floatx4*)(pbase + (t * 2 + 1) * 1024 + lane * 16);
      union { bf16 hh[4]; short4v s4; } uo;
#pragma unroll
      for (int r = 0; r < 4; r++) uo.hh[r] = (bf16)((oL[t][r] + aL[r]) * invL);
      *(short4v*)(orowL + t * 16 + 4 * g) = uo.s4;
#pragma unroll
      for (int r = 0; r < 4; r++) uo.hh[r] = (bf16)((oH[t][r] + aH[r]) * invH);
      *(short4v*)(orowH + t * 16 + 4 * g) = uo.s4;
    }
  }
}

// ---------------- launch ----------------
extern "C" void kernel_launch(void* const* d_in, const int* in_sizes, int n_in,
                              void* d_out, int out_size, void* d_ws, size_t ws_size,
                              hipStream_t stream) {
  const float* x  = (const float*)d_in[0];
  const float* Wq = (const float*)d_in[1];
  const float* Wk = (const float*)d_in[2];
  const float* Wv = (const float*)d_in[3];
  const float* Wo = (const float*)d_in[4];
  float* out = (float*)d_out;

  char* ws = (char*)d_ws;
  bf16* x_bf  = (bf16*)(ws);                    // 8 MiB
  bf16* WbigT = (bf16*)(ws + 8388608);          // 6 MiB
  bf16* WoT   = (bf16*)(ws + 14680064);         // 2 MiB
  bf16* q_ws  = (bf16*)(ws + 16777216);         // 8 MiB
  bf16* k_ws  = (bf16*)(ws + 25165824);         // 8 MiB
  bf16* v_ws  = (bf16*)(ws + 33554432);         // 8 MiB
  bf16* obuf  = (bf16*)(ws + 41943040);         // 8 MiB (total 48 MiB)

  hipFuncSetAttribute((const void*)gemm256_qkv,
                      hipFuncAttributeMaxDynamicSharedMemorySize, 114688);
  hipFuncSetAttribute((const void*)attn_kernel,
                      hipFuncAttributeMaxDynamicSharedMemorySize, 131072);

  prep_all<<<3072, 256, 0, stream>>>(x, Wq, Wk, Wv, Wo, x_bf, WbigT, WoT);
  gemm256_qkv<<<256, 512, 114688, stream>>>(x_bf, WbigT, q_ws, k_ws, v_ws);
  attn_kernel<<<256, 1024, 131072, stream>>>(q_ws, k_ws, v_ws, obuf);
  gemm_out<<<256, 256, 0, stream>>>(obuf, WoT, out, 1024, 8);
}

// Round 16
// 99.691 us; speedup vs baseline: 1.0025x; 1.0025x over previous
//
#include <hip/hip_runtime.h>

typedef __bf16 bf16;
typedef __attribute__((ext_vector_type(8))) short short8;
typedef __attribute__((ext_vector_type(4))) short short4v;
typedef __attribute__((ext_vector_type(4))) float floatx4;

#define DEVINL __device__ __forceinline__

// async global->LDS, 16B per lane. LDS dest = wave-uniform base + lane*16.
DEVINL void gll16(const void* g, void* l) {
  __builtin_amdgcn_global_load_lds((const __attribute__((address_space(1))) void*)g,
                                   (__attribute__((address_space(3))) void*)l, 16, 0, 0);
}

DEVINL float fast_exp2(float x) { return __builtin_amdgcn_exp2f(x); }

// scale * log2(e), folded into Q at projection time
#define QSCALE 0.18033688011112042f

// ---------------- fused prep: x->bf16 (blocks 0..2047) + weight transposes (2048..3071) ----
__global__ __launch_bounds__(256) void prep_all(const float* __restrict__ x,
                                                const float* __restrict__ Wq,
                                                const float* __restrict__ Wk,
                                                const float* __restrict__ Wv,
                                                const float* __restrict__ Wo,
                                                bf16* __restrict__ x_bf,
                                                bf16* __restrict__ WbigT,
                                                bf16* __restrict__ WoT) {
  __shared__ float tile[64][65];
  int bid = blockIdx.x;
  if (bid < 2048) {
    int i = (bid * 256 + threadIdx.x) * 8;
    float4 a = *(const float4*)(x + i);
    float4 b = *(const float4*)(x + i + 4);
    union { bf16 h[8]; short8 s; } u;
    u.h[0] = (bf16)a.x; u.h[1] = (bf16)a.y; u.h[2] = (bf16)a.z; u.h[3] = (bf16)a.w;
    u.h[4] = (bf16)b.x; u.h[5] = (bf16)b.y; u.h[6] = (bf16)b.z; u.h[7] = (bf16)b.w;
    *(short8*)(x_bf + i) = u.s;
    return;
  }
  int t = bid - 2048;
  int which = t >> 8;         // 0..3
  t &= 255;
  const float* in;
  bf16* out;
  int C, tilesC, tilesPerBatch;
  long inStride;
  if (which < 3) {
    in = which == 0 ? Wq : (which == 1 ? Wk : Wv);
    out = WbigT + (long)which * 1024 * 1024;
    C = 64; tilesC = 1; tilesPerBatch = 16; inStride = 65536;
  } else {
    in = Wo; out = WoT;
    C = 1024; tilesC = 16; tilesPerBatch = 256; inStride = 0;
  }
  int batch = t / tilesPerBatch;
  int tt = t % tilesPerBatch;
  int ri = tt / tilesC, ci = tt % tilesC;
  const float* src = in + batch * inStride;
  bf16* dst = out + batch * (long)65536 * (which < 3 ? 1 : 0);
  int tx = threadIdx.x & 63, ty = threadIdx.x >> 6;
#pragma unroll
  for (int i = 0; i < 16; i++) {
    int r = ty + i * 4;
    tile[r][tx] = src[(long)(ri * 64 + r) * C + ci * 64 + tx];
  }
  __syncthreads();
#pragma unroll
  for (int i = 0; i < 16; i++) {
    int c = ty + i * 4;
    dst[(long)(ci * 64 + c) * 1024 + ri * 64 + tx] = (bf16)tile[tx][c];
  }
}

// ---------------- QKV GEMM: 256x192 tile, BK=64, 8-phase counted-vmcnt schedule --------
// (R14-verified race-free schedule.)
__global__ __launch_bounds__(512, 2) void gemm256_qkv(const bf16* __restrict__ A,
                                                      const bf16* __restrict__ BT,
                                                      bf16* __restrict__ q_ws,
                                                      bf16* __restrict__ k_ws,
                                                      bf16* __restrict__ v_ws) {
  extern __shared__ char lds[];
  int swz = (blockIdx.x & 7) * 32 + (blockIdx.x >> 3);  // grid 256, XCD swizzle
  int bm = swz >> 4, bn = swz & 15;
  int tid = threadIdx.x, lane = tid & 63, wid = tid >> 6;
  int wm = wid >> 2, wn = wid & 3;
  int ql = lane & 15, g = lane >> 4;
  int sw = (ql & 7) << 4;
  char* ldsA = lds;            // [slot][half] 2*2*16KB = 64KB
  char* ldsB = lds + 65536;    // [slot] 2*24KB = 48KB

  const char* Abase = (const char*)A + (long)bm * 256 * 2048;
  const char* Bbase = (const char*)BT + (long)bn * 192 * 2048;
  int scb = ((tid & 7) * 16) ^ (((tid >> 3) & 7) << 4);  // pre-swizzled source col

  floatx4 acc[8][3] = {};
  short8 aF[4], bF[3];

#define STGA(kt_, h_) do {                                                         \
    _Pragma("unroll") for (int j_ = 0; j_ < 2; j_++)                               \
      gll16(Abase + (long)((h_) * 128 + j_ * 64 + (tid >> 3)) * 2048               \
                   + (kt_) * 128 + scb,                                            \
            ldsA + ((kt_) & 1) * 32768 + (h_) * 16384 + j_ * 8192 + wid * 1024);   \
  } while (0)
#define STGB(kt_, c_)                                                              \
    gll16(Bbase + (long)((c_) * 64 + (tid >> 3)) * 2048 + (kt_) * 128 + scb,       \
          ldsB + ((kt_) & 1) * 24576 + (c_) * 8192 + wid * 1024)
#define LDA(slot_, frh_, kk_) do {                                                 \
    _Pragma("unroll") for (int j_ = 0; j_ < 4; j_++)                               \
      aF[j_] = *(const short8*)(ldsA + (slot_) * 32768 + wm * 16384 +              \
               (((frh_) * 4 + j_) * 16 + ql) * 128 + (((kk_) * 64 + g * 16) ^ sw));\
  } while (0)
#define LDB(slot_, kk_) do {                                                       \
    _Pragma("unroll") for (int f_ = 0; f_ < 3; f_++)                               \
      bF[f_] = *(const short8*)(ldsB + (slot_) * 24576 +                           \
               (wn * 48 + f_ * 16 + ql) * 128 + (((kk_) * 64 + g * 16) ^ sw));     \
  } while (0)
#define MFMA12(frh_) do {                                                          \
    __builtin_amdgcn_s_setprio(1);                                                 \
    _Pragma("unroll") for (int j_ = 0; j_ < 4; j_++)                               \
      _Pragma("unroll") for (int f_ = 0; f_ < 3; f_++)                             \
        acc[(frh_) * 4 + j_][f_] = __builtin_amdgcn_mfma_f32_16x16x32_bf16(        \
            aF[j_], bF[f_], acc[(frh_) * 4 + j_][f_], 0, 0, 0);                    \
    __builtin_amdgcn_s_setprio(0);                                                 \
  } while (0)
#define BAR __builtin_amdgcn_s_barrier()
#define LG0 asm volatile("s_waitcnt lgkmcnt(0)" ::: "memory")

  // prologue: B(0):3, A(0):4, B(1):3 = 10 loads
  STGB(0, 0); STGB(0, 1); STGB(0, 2);
  STGA(0, 0); STGA(0, 1);
  STGB(1, 0); STGB(1, 1); STGB(1, 2);

  for (int it = 0; it < 8; it++) {
    int b1 = 2 * it + 1, a2 = 2 * it + 2, b2 = 2 * it + 3;
    bool more = it < 7;
    // P1
    asm volatile("s_waitcnt vmcnt(3)" ::: "memory");
    BAR;
    LDA(0, 0, 0); LDB(0, 0);
    STGA(b1, 0);
    BAR; LG0; MFMA12(0); BAR;
    // P2
    LDA(0, 1, 0);
    STGA(b1, 1);
    BAR; LG0; MFMA12(1); BAR;
    // P3 — no stage
    LDA(0, 0, 1); LDB(0, 1);
    BAR; LG0; MFMA12(0); BAR;
    // P4
    LDA(0, 1, 1);
    if (more) { STGB(a2, 0); STGB(a2, 1); STGB(a2, 2); }
    BAR; LG0; MFMA12(1); BAR;
    // P5
    if (more) { asm volatile("s_waitcnt vmcnt(3)" ::: "memory"); }
    else      { asm volatile("s_waitcnt vmcnt(0)" ::: "memory"); }
    BAR;
    LDA(1, 0, 0); LDB(1, 0);
    if (more) STGA(a2, 0);
    BAR; LG0; MFMA12(0); BAR;
    // P6
    LDA(1, 1, 0);
    if (more) STGA(a2, 1);
    BAR; LG0; MFMA12(1); BAR;
    // P7 — no stage
    LDA(1, 0, 1); LDB(1, 1);
    BAR; LG0; MFMA12(0); BAR;
    // P8
    LDA(1, 1, 1);
    if (more) { STGB(b2, 0); STGB(b2, 1); STGB(b2, 2); }
    BAR; LG0; MFMA12(1); BAR;
  }
#undef STGA
#undef STGB
#undef LDA
#undef LDB
#undef MFMA12
#undef BAR
#undef LG0

  // ---- epilogue ----
#pragma unroll
  for (int fr = 0; fr < 8; fr++)
#pragma unroll
    for (int fc = 0; fc < 3; fc++) {
      int local_c = wn * 48 + fc * 16 + ql;
      int cg = bn * 192 + local_c;
      if (cg < 2048) {
        bf16* dst = (cg < 1024) ? q_ws : k_ws;
        float scale = (cg < 1024) ? QSCALE : 1.0f;
        int h = (cg >> 6) & 15, e = cg & 63;
#pragma unroll
        for (int i = 0; i < 4; i++) {
          int r = bm * 256 + wm * 128 + fr * 16 + g * 4 + i;
          int b = r >> 11, s = r & 2047;
          long bh = (long)b * 16 + h;
          dst[(bh * 2048 + s) * 64 + e] = (bf16)(acc[fr][fc][i] * scale);
        }
      }
    }

  if (bn >= 10) {
    __syncthreads();
#pragma unroll
    for (int fr = 0; fr < 8; fr++)
#pragma unroll
      for (int fc = 0; fc < 3; fc++) {
        int local_c = wn * 48 + fc * 16 + ql;
        int cg = bn * 192 + local_c;
        if (cg >= 2048) {
          int ls0 = wm * 128 + fr * 16 + g * 4;
          int s6 = ls0 & 63;
          // sigma16: key 32kk+16b'+4g+r' -> pos 32kk+8g+4b'+r'
          int sp = (ls0 & ~63) | (s6 & 35) | ((s6 & 12) << 1) | ((s6 & 16) >> 2);
          union { bf16 hh[4]; short4v s4; } u;
#pragma unroll
          for (int i = 0; i < 4; i++) u.hh[i] = (bf16)acc[fr][fc][i];
          *(short4v*)(lds + local_c * 512 + ((sp * 2) ^ ((local_c & 7) << 4))) = u.s4;
        }
      }
    __syncthreads();
    int b = bm >> 3;
    long sbase = (long)(bm & 7) * 256;
#pragma unroll
    for (int j = 0; j < 12; j++) {
      int local_c = wid * 24 + j * 2 + (lane >> 5);
      int cg = bn * 192 + local_c;
      if (cg >= 2048) {
        int chunk = lane & 31;
        int h = (cg >> 6) & 15, e = cg & 63;
        long bh = (long)b * 16 + h;
        char* dstp = (char*)v_ws + ((bh * 64 + e) * 2048 + sbase) * 2 + chunk * 16;
        *(short8*)dstp = *(const short8*)(lds + local_c * 512 + ((chunk * 16) ^ ((local_c & 7) << 4)));
      }
    }
  }
}

// ---------------- GEMM (output projection): 128x128 tile, 4 waves, 2-phase pipelined ----
__global__ __launch_bounds__(256) void gemm_out(const bf16* __restrict__ A,
                                                const bf16* __restrict__ BT,
                                                float* __restrict__ Cout,
                                                int N, int gridN) {
  int cpx = gridDim.x >> 3;
  int swz = (blockIdx.x & 7) * cpx + (blockIdx.x >> 3);
  int bm = swz / gridN, bn = swz % gridN;
  __shared__ char lds[65536];  // A slots @0,16K ; B slots @32K,48K
  int tid = threadIdx.x;
  int lane = tid & 63, wid = tid >> 6;
  int wr = wid >> 1, wc = wid & 1;
  floatx4 acc[4][4] = {};
  const char* Abase = (const char*)A + (long)bm * 128 * 2048;
  const char* Bbase = (const char*)BT + (long)bn * 128 * 2048;
  int scb = ((tid & 7) * 16) ^ (((tid >> 3) & 7) << 4);

#define OSTG(kt_) do {                                                             \
    char* la_ = lds + ((kt_) & 1) * 16384;                                         \
    char* lb_ = lds + 32768 + ((kt_) & 1) * 16384;                                 \
    _Pragma("unroll") for (int q_ = 0; q_ < 4; q_++) {                             \
      gll16(Abase + (long)(q_ * 32 + (tid >> 3)) * 2048 + (kt_) * 128 + scb,       \
            la_ + q_ * 4096 + wid * 1024);                                         \
      gll16(Bbase + (long)(q_ * 32 + (tid >> 3)) * 2048 + (kt_) * 128 + scb,       \
            lb_ + q_ * 4096 + wid * 1024);                                         \
    }                                                                              \
  } while (0)

  OSTG(0);
  for (int kt = 0; kt < 16; kt++) {
    if (kt < 15) {
      OSTG(kt + 1);
      asm volatile("s_waitcnt vmcnt(8)" ::: "memory");
    } else {
      asm volatile("s_waitcnt vmcnt(0)" ::: "memory");
    }
    __builtin_amdgcn_s_barrier();
    char* la = lds + (kt & 1) * 16384;
    char* lb = lds + 32768 + (kt & 1) * 16384;
#pragma unroll
    for (int kk = 0; kk < 2; kk++) {
      short8 a[4], b[4];
#pragma unroll
      for (int mi = 0; mi < 4; mi++) {
        int row = wr * 64 + mi * 16 + (lane & 15);
        int col = (kk * 64 + (lane >> 4) * 16) ^ ((row & 7) << 4);
        a[mi] = *(const short8*)(la + row * 128 + col);
      }
#pragma unroll
      for (int ni = 0; ni < 4; ni++) {
        int row = wc * 64 + ni * 16 + (lane & 15);
        int col = (kk * 64 + (lane >> 4) * 16) ^ ((row & 7) << 4);
        b[ni] = *(const short8*)(lb + row * 128 + col);
      }
#pragma unroll
      for (int mi = 0; mi < 4; mi++)
#pragma unroll
        for (int ni = 0; ni < 4; ni++)
          acc[mi][ni] = __builtin_amdgcn_mfma_f32_16x16x32_bf16(a[mi], b[ni], acc[mi][ni], 0, 0, 0);
    }
    __builtin_amdgcn_s_barrier();
  }
#undef OSTG

#pragma unroll
  for (int mi = 0; mi < 4; mi++)
#pragma unroll
    for (int ni = 0; ni < 4; ni++)
#pragma unroll
      for (int i = 0; i < 4; i++) {
        int r = bm * 128 + wr * 64 + mi * 16 + (lane >> 4) * 4 + i;
        int c = bn * 128 + wc * 64 + ni * 16 + (lane & 15);
        Cout[(long)r * N + c] = acc[mi][ni][i];
      }
}

// ---------------- flash attention: KV-split x2 in one 1024-thread block (R14-verified) ----
// grid 256 (1 block/CU, XCD-bijective). Block = 16 waves = 2 groups of 8; group g
// processes keys [g*1024, g*1024+1024) for the SAME 256 q-rows (32 q-rows/wave).
// Max-free softmax (P=exp2(S)); combine additive: O=O0+O1, l=l0+l1 via dead LDS.
// l via mfma(ones,P) — measured faster than VALU-l (R15 A/B: MFMA pipe has slack,
// VALU is the critical chain in the softmax window). 4-deep K/V buffers, counted
// vmcnt(2) + raw s_barrier per leg.
__global__ __launch_bounds__(1024, 4) void attn_kernel(const bf16* __restrict__ q_ws,
                                                       const bf16* __restrict__ k_ws,
                                                       const bf16* __restrict__ v_ws,
                                                       bf16* __restrict__ obuf) {
  extern __shared__ char lds[];  // [grp][ kbuf 4x8KB | vbuf 4x8KB ] = 2 x 64KB
  int wgid = ((blockIdx.x & 7) << 5) + (blockIdx.x >> 3);  // bijective, 256 = 8*32
  int qt = wgid & 7;
  int bh = wgid >> 3;
  int b = bh >> 4, h = bh & 15;
  int tid = threadIdx.x, lane = tid & 63, wid = tid >> 6;  // wid 0..15
  int grp = wid >> 3, w8 = wid & 7;
  int ql = lane & 15, g = lane >> 4;
  char* kbuf = lds + grp * 65536;
  char* vbuf = kbuf + 32768;

  const char* kbase = (const char*)k_ws + (long)bh * 2048 * 128 + (long)grp * 16 * 64 * 128;
  const char* vbase = (const char*)v_ws + (long)bh * 64 * 4096 + (long)grp * 16 * 128;

  int srow = w8 * 8 + (lane >> 3);
  int scb = ((lane & 7) * 16) ^ (((lane >> 3) & 7) << 4);

#define STAGE(t_) do {                                                              \
    gll16(kbase + ((long)(t_) * 64 + srow) * 128 + scb,                             \
          kbuf + ((t_) & 3) * 8192 + w8 * 1024);                                    \
    gll16(vbase + (long)srow * 4096 + (long)(t_) * 128 + scb,                       \
          vbuf + ((t_) & 3) * 8192 + w8 * 1024);                                    \
  } while (0)

#define WAIT2_BAR do {                                                              \
    asm volatile("s_waitcnt vmcnt(2)" ::: "memory");                                \
    __builtin_amdgcn_s_barrier();                                                   \
    asm volatile("" ::: "memory");                                                  \
  } while (0)

  int sw = (ql & 7) << 4;
  int fof0 = ql * 128 + ((g * 16) ^ sw);        // kk = 0
  int fof1 = ql * 128 + ((64 + g * 16) ^ sw);   // kk = 1

  const bf16* qrowL = q_ws + ((long)bh * 2048 + qt * 256 + w8 * 32 + ql) * 64 + 8 * g;
  short8 qL0 = *(const short8*)(qrowL);
  short8 qL1 = *(const short8*)(qrowL + 32);
  short8 qH0 = *(const short8*)(qrowL + 1024);       // +16 rows
  short8 qH1 = *(const short8*)(qrowL + 1024 + 32);

  union { bf16 hh[8]; short8 s; } uo1;
#pragma unroll
  for (int i = 0; i < 8; i++) uo1.hh[i] = (bf16)1.0f;
  const short8 ones = uo1.s;

  floatx4 lL = {}, lH = {};
  floatx4 oL[4] = {}, oH[4] = {};
  floatx4 saL[4], saH[4];
  short8 pbL[2], pbH[2];

#define QKSTEP(kc) do {                                                             \
    __builtin_amdgcn_s_setprio(1);                                                  \
    _Pragma("unroll") for (int t_ = 0; t_ < 4; t_++) {                              \
      short8 kf = *(const short8*)((kc) + fof0 + t_ * 2048);                        \
      saL[t_] = __builtin_amdgcn_mfma_f32_16x16x32_bf16(kf, qL0, (floatx4){}, 0, 0, 0); \
      saH[t_] = __builtin_amdgcn_mfma_f32_16x16x32_bf16(kf, qH0, (floatx4){}, 0, 0, 0); \
    }                                                                               \
    _Pragma("unroll") for (int t_ = 0; t_ < 4; t_++) {                              \
      short8 kf = *(const short8*)((kc) + fof1 + t_ * 2048);                        \
      saL[t_] = __builtin_amdgcn_mfma_f32_16x16x32_bf16(kf, qL1, saL[t_], 0, 0, 0); \
      saH[t_] = __builtin_amdgcn_mfma_f32_16x16x32_bf16(kf, qH1, saH[t_], 0, 0, 0); \
    }                                                                               \
    __builtin_amdgcn_s_setprio(0);                                                  \
  } while (0)

#define SM_HALF(sa, pb, l_acc, o_acc) do {                                          \
    if (__builtin_expect(l_acc[0] > 1e30f, 0)) {                                    \
      const float c_ = 7.8886091e-31f; /* 2^-100 */                                 \
      _Pragma("unroll") for (int t_ = 0; t_ < 4; t_++)                              \
        _Pragma("unroll") for (int i_ = 0; i_ < 4; i_++) o_acc[t_][i_] *= c_;       \
      _Pragma("unroll") for (int i_ = 0; i_ < 4; i_++) l_acc[i_] *= c_;             \
    }                                                                               \
    _Pragma("unroll") for (int kk_ = 0; kk_ < 2; kk_++) {                           \
      union { bf16 hh[8]; short8 s; } up_;                                          \
      _Pragma("unroll") for (int r_ = 0; r_ < 4; r_++)                              \
        up_.hh[r_] = (bf16)fast_exp2(sa[2 * kk_][r_]);                              \
      _Pragma("unroll") for (int r_ = 0; r_ < 4; r_++)                              \
        up_.hh[4 + r_] = (bf16)fast_exp2(sa[2 * kk_ + 1][r_]);                      \
      pb[kk_] = up_.s;                                                              \
    }                                                                               \
  } while (0)

#define SMSTEP do { SM_HALF(saL, pbL, lL, oL); SM_HALF(saH, pbH, lH, oH); } while (0)

#define PVSTEP(vc) do {                                                             \
    __builtin_amdgcn_s_setprio(1);                                                  \
    lL = __builtin_amdgcn_mfma_f32_16x16x32_bf16(ones, pbL[0], lL, 0, 0, 0);        \
    lL = __builtin_amdgcn_mfma_f32_16x16x32_bf16(ones, pbL[1], lL, 0, 0, 0);        \
    lH = __builtin_amdgcn_mfma_f32_16x16x32_bf16(ones, pbH[0], lH, 0, 0, 0);        \
    lH = __builtin_amdgcn_mfma_f32_16x16x32_bf16(ones, pbH[1], lH, 0, 0, 0);        \
    _Pragma("unroll") for (int t_ = 0; t_ < 4; t_++) {                              \
      short8 vf = *(const short8*)((vc) + fof0 + t_ * 2048);                        \
      oL[t_] = __builtin_amdgcn_mfma_f32_16x16x32_bf16(vf, pbL[0], oL[t_], 0, 0, 0);\
      oH[t_] = __builtin_amdgcn_mfma_f32_16x16x32_bf16(vf, pbH[0], oH[t_], 0, 0, 0);\
    }                                                                               \
    _Pragma("unroll") for (int t_ = 0; t_ < 4; t_++) {                              \
      short8 vf = *(const short8*)((vc) + fof1 + t_ * 2048);                        \
      oL[t_] = __builtin_amdgcn_mfma_f32_16x16x32_bf16(vf, pbL[1], oL[t_], 0, 0, 0);\
      oH[t_] = __builtin_amdgcn_mfma_f32_16x16x32_bf16(vf, pbH[1], oH[t_], 0, 0, 0);\
    }                                                                               \
    __builtin_amdgcn_s_setprio(0);                                                  \
  } while (0)

  // ---- prologue ----
  STAGE(0); STAGE(1);
  WAIT2_BAR;
  QKSTEP(kbuf + 0 * 8192);
  STAGE(2);
  SMSTEP;
  WAIT2_BAR;
  STAGE(3);
  QKSTEP(kbuf + 1 * 8192);

  // ---- main loop: legs t = 1..13 ----
  for (int t = 1; t <= 13; t++) {
    PVSTEP(vbuf + ((t - 1) & 3) * 8192);
    SMSTEP;
    WAIT2_BAR;
    if (t <= 12) STAGE(t + 3);
    QKSTEP(kbuf + ((t + 1) & 3) * 8192);
  }

  // ---- leg 14 (drain to 0 for the last tile) ----
  PVSTEP(vbuf + (13 & 3) * 8192);
  SMSTEP;
  __syncthreads();               // vmcnt(0): tile 15 landed
  QKSTEP(kbuf + (15 & 3) * 8192);

  // ---- leg 15 ----
  PVSTEP(vbuf + (14 & 3) * 8192);
  SMSTEP;
  PVSTEP(vbuf + (15 & 3) * 8192);

#undef STAGE
#undef WAIT2_BAR
#undef QKSTEP
#undef SM_HALF
#undef SMSTEP
#undef PVSTEP

  // ---- combine: O = O0 + O1, l = l0 + l1 (all K/V buffers dead) ----
  __syncthreads();
  if (grp == 1) {
    char* pbase = lds + 65536 + w8 * 8192;  // group 1's own (dead) region
#pragma unroll
    for (int t = 0; t < 4; t++) {
      *(floatx4*)(pbase + (t * 2 + 0) * 1024 + lane * 16) = oL[t];
      *(floatx4*)(pbase + (t * 2 + 1) * 1024 + lane * 16) = oH[t];
    }
    *(float2*)(lds + w8 * 512 + lane * 8) = make_float2(lL[0], lH[0]);
  }
  __syncthreads();
  if (grp == 0) {
    float2 lp = *(const float2*)(lds + w8 * 512 + lane * 8);
    const char* pbase = lds + 65536 + w8 * 8192;
    float invL = 1.f / (lL[0] + lp.x);
    float invH = 1.f / (lH[0] + lp.y);
    int s = qt * 256 + w8 * 32 + ql;
    bf16* orowL = obuf + ((long)b * 2048 + s) * 1024 + h * 64;
    bf16* orowH = orowL + 16 * 1024;
#pragma unroll
    for (int t = 0; t < 4; t++) {
      floatx4 aL = *(const floatx4*)(pbase + (t * 2 + 0) * 1024 + lane * 16);
      floatx4 aH = *(const floatx4*)(pbase + (t * 2 + 1) * 1024 + lane * 16);
      union { bf16 hh[4]; short4v s4; } uo;
#pragma unroll
      for (int r = 0; r < 4; r++) uo.hh[r] = (bf16)((oL[t][r] + aL[r]) * invL);
      *(short4v*)(orowL + t * 16 + 4 * g) = uo.s4;
#pragma unroll
      for (int r = 0; r < 4; r++) uo.hh[r] = (bf16)((oH[t][r] + aH[r]) * invH);
      *(short4v*)(orowH + t * 16 + 4 * g) = uo.s4;
    }
  }
}

// ---------------- launch ----------------
extern "C" void kernel_launch(void* const* d_in, const int* in_sizes, int n_in,
                              void* d_out, int out_size, void* d_ws, size_t ws_size,
                              hipStream_t stream) {
  const float* x  = (const float*)d_in[0];
  const float* Wq = (const float*)d_in[1];
  const float* Wk = (const float*)d_in[2];
  const float* Wv = (const float*)d_in[3];
  const float* Wo = (const float*)d_in[4];
  float* out = (float*)d_out;

  char* ws = (char*)d_ws;
  bf16* x_bf  = (bf16*)(ws);                    // 8 MiB
  bf16* WbigT = (bf16*)(ws + 8388608);          // 6 MiB
  bf16* WoT   = (bf16*)(ws + 14680064);         // 2 MiB
  bf16* q_ws  = (bf16*)(ws + 16777216);         // 8 MiB
  bf16* k_ws  = (bf16*)(ws + 25165824);         // 8 MiB
  bf16* v_ws  = (bf16*)(ws + 33554432);         // 8 MiB
  bf16* obuf  = (bf16*)(ws + 41943040);         // 8 MiB (total 48 MiB)

  hipFuncSetAttribute((const void*)gemm256_qkv,
                      hipFuncAttributeMaxDynamicSharedMemorySize, 114688);
  hipFuncSetAttribute((const void*)attn_kernel,
                      hipFuncAttributeMaxDynamicSharedMemorySize, 131072);

  prep_all<<<3072, 256, 0, stream>>>(x, Wq, Wk, Wv, Wo, x_bf, WbigT, WoT);
  gemm256_qkv<<<256, 512, 114688, stream>>>(x_bf, WbigT, q_ws, k_ws, v_ws);
  attn_kernel<<<256, 1024, 131072, stream>>>(q_ws, k_ws, v_ws, obuf);
  gemm_out<<<256, 256, 0, stream>>>(obuf, WoT, out, 1024, 8);
}